// Round 17
// baseline (192.749 us; speedup 1.0000x reference)
//
#include <hip/hip_runtime.h>
#include <hip/hip_bf16.h>

using bf16 = __hip_bfloat16;
typedef __attribute__((ext_vector_type(8))) short short8;
typedef __attribute__((ext_vector_type(4))) float f32x4;
typedef __attribute__((ext_vector_type(4))) int i32x4;

#define QP   1088   // padded flat spatial per image (30*30=900 + tail to 1088)
#define QO   1024   // x1 q-extent per image (4 tiles * 256)
#define KTOT 2304
#define NIMG 64
#define CCH  256
#define HW   28
#define PLN  784
#define AROWS 318   // 256 + 62 tap reach

__device__ __forceinline__ void gload_lds16(const void* g, void* l) {
  __builtin_amdgcn_global_load_lds((const __attribute__((address_space(1))) void*)g,
                                   (__attribute__((address_space(3))) void*)l, 16, 0, 0);
}

// ------- init: zero Xp borders/tails (i8) + zero rs1/rs2 --------------------
// special rows/image: 0..29 (30) + 870..899 (30) + 900..1087 (188) +
// cols{0,29} of h=1..28 (56) = 304 rows -> 4864 chunk tasks.
__global__ __launch_bounds__(256) void kinit(int8_t* __restrict__ xp1,
                                             int8_t* __restrict__ xp2,
                                             i32x4* __restrict__ rsz) {
  const int b = blockIdx.x;
  const int t = threadIdx.x;
  const i32x4 z = {0, 0, 0, 0};
  if (b < 128) {
    const int n = b >> 1;
    int8_t* xp = (b & 1) ? xp2 : xp1;
#pragma unroll
    for (int p = 0; p < 19; ++p) {
      const int task = p * 256 + t;
      if (task < 4864) {
        const int r = task >> 4, l16 = task & 15;
        int q;
        if (r < 30) q = r;
        else if (r < 60) q = 870 + (r - 30);
        else if (r < 248) q = 900 + (r - 60);
        else { const int k = r - 248; q = (1 + (k >> 1)) * 30 + ((k & 1) ? 29 : 0); }
        ((i32x4*)(xp + ((size_t)n * QP + q) * CCH))[l16] = z;
      }
    }
  } else {
    // rs1+rs2: 2*64*1088 f32 = 34816 chunks over 120 blocks
    const int idx = (b - 128) * 256 + t;
#pragma unroll
    for (int k = 0; k < 2; ++k) {
      const int j = idx + k * 30720;
      if (j < 34816) rsz[j] = z;
    }
  }
}

// ---------------- weight prep ------------------------------------------------
__global__ __launch_bounds__(256) void kwprep(const float* __restrict__ w1,
                                              const float* __restrict__ w2,
                                              int8_t* __restrict__ aw1,
                                              int8_t* __restrict__ aw2,
                                              float* __restrict__ am1,
                                              float* __restrict__ am2) {
  const int o = blockIdx.x & 255;
  const float* w = (blockIdx.x >> 8) ? w2 : w1;
  int8_t* aw = (blockIdx.x >> 8) ? aw2 : aw1;
  float* am = (blockIdx.x >> 8) ? am2 : am1;
  const int t = threadIdx.x;
  const int lane = t & 63, wid = t >> 6;
  const float* wo = w + (size_t)o * KTOT;
  float v[9];
  double s = 0.0;
#pragma unroll
  for (int j = 0; j < 9; ++j) { v[j] = wo[t * 9 + j]; s += (double)v[j]; }
  __shared__ double red[4];
#pragma unroll
  for (int m = 32; m >= 1; m >>= 1) s += __shfl_xor(s, m);
  if (lane == 0) red[wid] = s;
  __syncthreads();
  const double mean = (red[0] + red[1] + red[2] + red[3]) * (1.0 / 2304.0);
  __syncthreads();
  double sq = 0.0;
#pragma unroll
  for (int j = 0; j < 9; ++j) { const double d = (double)v[j] - mean; sq += d * d; }
#pragma unroll
  for (int m = 32; m >= 1; m >>= 1) sq += __shfl_xor(sq, m);
  if (lane == 0) red[wid] = sq;
  __syncthreads();
  const double alpha = sqrt((red[0] + red[1] + red[2] + red[3]) * (1.0 / 2304.0));
#pragma unroll
  for (int j = 0; j < 9; ++j) {
    const double d = (double)v[j] - mean;
    const int sg = d > 0.0 ? 1 : (d < 0.0 ? -1 : 0);
    aw[(size_t)o * KTOT + j * CCH + t] = (int8_t)sg;
  }
  if (t == 0) { am[o] = (float)alpha; am[CCH + o] = (float)mean; }
}

// -------- activation signs + row sums + transposed residual -----------------
__global__ __launch_bounds__(256) void kaprep(const float* __restrict__ x,
                                              const float* __restrict__ alpha,
                                              const float* __restrict__ beta,
                                              int8_t* __restrict__ xp,
                                              float* __restrict__ rs,
                                              float* __restrict__ xT) {
  const int n = blockIdx.x / HW;
  const int h = blockIdx.x % HW;
  const int c = threadIdx.x;
  const float a = alpha[c], bt = beta[c];
  const float* src = x + ((size_t)(n * CCH + c)) * PLN + h * HW;
  __shared__ int8_t tile[CCH][HW];
#pragma unroll
  for (int j = 0; j < 7; ++j) {
    float4 f = ((const float4*)src)[j];
    float vv[4] = {f.x, f.y, f.z, f.w};
#pragma unroll
    for (int e = 0; e < 4; ++e) {
      const float xa = (vv[e] - bt) / a;
      const float sg = xa > 0.f ? 1.f : (xa < 0.f ? -1.f : 0.f);
      tile[c][j * 4 + e] = (int8_t)__float2int_rn(sg * a + bt);
      xT[((size_t)n * PLN + h * HW + j * 4 + e) * CCH + c] = vv[e];
    }
  }
  __syncthreads();
  int8_t* dst = xp + ((size_t)n * QP + (h + 1) * 30 + 1) * CCH;
#pragma unroll
  for (int ww = 0; ww < HW; ++ww) dst[ww * CCH + c] = tile[c][ww];
  const int ww = c >> 3, sub = c & 7;
  if (ww < HW) {
    int s = 0;
#pragma unroll
    for (int cc = 0; cc < 32; ++cc) s += (int)tile[sub * 32 + cc][ww];
    s += __shfl_xor(s, 4); s += __shfl_xor(s, 2); s += __shfl_xor(s, 1);
    if (sub == 0) rs[(size_t)n * QP + (h + 1) * 30 + 1 + ww] = (float)s;
  }
}

// ---------------- implicit-GEMM conv: 256x256 tile, 1 block/CU --------------
// 256 blocks (64 img x 4 q-tiles of 256), 8 waves (512 thr), wave tile 128x64
// (acc[8][4]). Persistent A: 318 rows x 256B (81.4KB, row-local chunk-XOR).
// B ring 3 x 16KB (packed 128 lds-rows x 128B, r9 layout). vmcnt(2) counted.
// EPI1 (D[q][o]): two-pass LDS-staged x1T + Xp2 writeout, rs2 atomics.
// EPI2 (D[o][q] swapped): w-contiguous out writes, contiguous x1 reads.
template <int EPI>
__global__ __launch_bounds__(512, 2) void kconv(
    const int8_t* __restrict__ xp, const int8_t* __restrict__ aw,
    const float* __restrict__ am, const float* __restrict__ rs,
    const float* __restrict__ bng, const float* __restrict__ bnb,
    const float* __restrict__ bnm, const float* __restrict__ bnv,
    const float* __restrict__ pos, const float* __restrict__ neg,
    const float* __restrict__ xT, const bf16* __restrict__ x1r,
    const float* __restrict__ a2, const float* __restrict__ b2,
    int8_t* __restrict__ xpn, bf16* __restrict__ x1t,
    float* __restrict__ rsn, float* __restrict__ out)
{
  __shared__ char lds[130560];          // A 81408 @0 + B ring 3*16384 @81408
  char* ldsB = lds + 81408;
  float* ldsT = (float*)(lds + 129536); // last 1KB (dead post-loop)
  const int bid0 = blockIdx.x;
  const int bid = (bid0 & 7) * 32 + (bid0 >> 3);   // XCD swizzle (256=8*32)
  const int n = bid >> 2;
  const int qt = (bid & 3) * 256;
  const int t = threadIdx.x;
  const int lane = t & 63, wid = t >> 6;
  const int rw = wid >> 2, cw = wid & 3;

  // B staging: 1024 chunks; thread t does chunks t and t+512 (rho and rho+64)
  const int rho = t >> 3;               // lds-row 0..63 (second task +64)
  const int cch = t & 7;
  const int clg = cch ^ (rho & 7);      // same for both tasks ((rho+64)&7==rho&7)
  const int pW = clg >> 2;
  const int k16W = clg & 3;
  const int8_t* baseB = aw + ((size_t)(2 * rho + pW)) * KTOT + k16W * 16;

  i32x4 acc[8][4];
#pragma unroll
  for (int i = 0; i < 8; ++i)
#pragma unroll
    for (int j = 0; j < 4; ++j) acc[i][j] = (i32x4){0, 0, 0, 0};

  const int r16 = lane & 15;
  const int g = lane >> 4;
  const int g4 = g * 4;
  const int rsh = r16 >> 1;
  const int pc0 = ((r16 & 1) * 4 + g) ^ rsh;
  // operand bases: EPI1 rows=pixels(A), cols=weights(B); EPI2 swapped
  const int aoff = (EPI == 1) ? rw * 128 : cw * 64;   // pixel-row base in A
  const int bro  = (EPI == 1) ? cw * 32  : rw * 64;   // weight lds-row base

  auto STAGE_B = [&](int buf, int ks) {
    const int8_t* sB = baseB + (size_t)ks * 64;
    char* dB = ldsB + buf * 16384 + rho * 128 + cch * 16;
    gload_lds16(sB, dB);
    gload_lds16(sB + (size_t)128 * KTOT, dB + 8192);
  };

  {  // persistent-A prologue: 318 rows x 16 chunks = 5088 tasks
    const int8_t* imgA = xp + ((size_t)(n * QP + qt)) * CCH;
#pragma unroll
    for (int i = 0; i < 10; ++i) {
      const int task = t + i * 512;
      if (task < 5088) {
        const int rr = task >> 4, pc = task & 15;
        gload_lds16(imgA + (size_t)rr * CCH + ((pc ^ (rr & 15)) * 16),
                    lds + rr * 256 + pc * 16);
      }
    }
  }
  STAGE_B(0, 0);
  STAGE_B(1, 1);
  asm volatile("s_waitcnt vmcnt(2)" ::: "memory");   // A + B0 landed
  __builtin_amdgcn_s_barrier();

#pragma unroll
  for (int ks = 0; ks < 36; ++ks) {
    const int tap = ks >> 2, ksl = ks & 3;
    const int shc = (tap / 3) * 30 + (tap % 3);
    const int cur = ks % 3;
    const int achunk = ((ksl * 4 + g) ^ ((r16 + shc) & 15)) * 16;
    const char* pA = lds + (shc + aoff + r16) * 256 + achunk;
    const char* pB = ldsB + cur * 16384;
    i32x4 fR[8], fC[4];
    if constexpr (EPI == 1) {
#pragma unroll
      for (int m = 0; m < 8; ++m) fR[m] = *(const i32x4*)&pA[m * 4096];
#pragma unroll
      for (int nn = 0; nn < 4; ++nn)
        fC[nn] = *(const i32x4*)&pB[(bro + nn * 8 + rsh) * 128 + pc0 * 16];
    } else {
#pragma unroll
      for (int m = 0; m < 8; ++m)
        fR[m] = *(const i32x4*)&pB[(bro + m * 8 + rsh) * 128 + pc0 * 16];
#pragma unroll
      for (int nn = 0; nn < 4; ++nn) fC[nn] = *(const i32x4*)&pA[nn * 4096];
    }
    if (ks < 34) STAGE_B((ks + 2) % 3, ks + 2);
    __builtin_amdgcn_s_setprio(1);
#pragma unroll
    for (int m = 0; m < 8; ++m)
#pragma unroll
      for (int nn = 0; nn < 4; ++nn)
        acc[m][nn] = __builtin_amdgcn_mfma_i32_16x16x64_i8(
            fR[m], fC[nn], acc[m][nn], 0, 0, 0);
    __builtin_amdgcn_s_setprio(0);
    if (ks < 34) {
      asm volatile("s_waitcnt vmcnt(2)" ::: "memory");
    } else {
      asm volatile("s_waitcnt vmcnt(0)" ::: "memory");
    }
    __builtin_amdgcn_s_barrier();
  }

  // ---- per-block T[0..255] into dead LDS ------------------------------------
  if (t < 256) {
    const float* rrow = rs + (size_t)n * QP + qt + t;
    float s = 0.f;
#pragma unroll
    for (int kh = 0; kh < 3; ++kh)
#pragma unroll
      for (int kw = 0; kw < 3; ++kw) s += rrow[kh * 30 + kw];
    ldsT[t] = s;
  }

  if constexpr (EPI == 1) {
    // D[q = qt + rw*128 + m*16 + g4 + r][o = cw*64 + nn*16 + r16]
    int oc[4];
    float invc[4], addc[4], ppc[4], ngc[4], awc[4], mwc[4], aac[4], bbc[4];
#pragma unroll
    for (int nn = 0; nn < 4; ++nn) {
      const int o = cw * 64 + nn * 16 + r16;
      oc[nn] = o;
      const float inv = bng[o] / sqrtf(bnv[o] + 1e-5f);
      invc[nn] = inv;
      addc[nn] = bnb[o] - bnm[o] * inv;
      ppc[nn] = pos[o]; ngc[nn] = neg[o];
      awc[nn] = am[o];  mwc[nn] = am[CCH + o];
      aac[nn] = a2[o];  bbc[nn] = b2[o];
    }
    __syncthreads();                      // ldsT visible; loop LDS reusable
    short* tb = (short*)lds;              // [256 o][136 q-half] 69.6KB
    int8_t* xpb = (int8_t*)(lds + 69632); // [128 q-half][256 o] 32KB
#pragma unroll
    for (int h = 0; h < 2; ++h) {
      if (rw == h) {
#pragma unroll
        for (int m = 0; m < 8; ++m) {
#pragma unroll
          for (int r = 0; r < 4; ++r) {
            const int qlh = m * 16 + g4 + r;        // 0..127 within half
            const int q = qt + h * 128 + qlh;
            const int hh = q / 30, ww2 = q % 30;
            if (hh < HW && ww2 < HW) {
              const float tq = ldsT[h * 128 + qlh];
              const float* xrow = xT + ((size_t)n * PLN + hh * HW + ww2) * CCH;
              float rowsum = 0.f;
#pragma unroll
              for (int nn = 0; nn < 4; ++nn) {
                const int ol = oc[nn];
                float v = awc[nn] * (float)acc[m][nn][r] + mwc[nn] * tq;
                v = v * invc[nn] + addc[nn];
                v += xrow[ol];
                v = v > 0.f ? ppc[nn] * v : ngc[nn] * v;
                const float d = v - bbc[nn];
                const float sg = d > 0.f ? 1.f : (d < 0.f ? -1.f : 0.f);
                const float bv = sg * aac[nn] + bbc[nn];
                rowsum += bv;
                xpb[qlh * 256 + ol] = (int8_t)__float2int_rn(bv);
                bf16 hb = __float2bfloat16(v);
                tb[ol * 136 + qlh] = *reinterpret_cast<short*>(&hb);
              }
              rowsum += __shfl_xor(rowsum, 8); rowsum += __shfl_xor(rowsum, 4);
              rowsum += __shfl_xor(rowsum, 2); rowsum += __shfl_xor(rowsum, 1);
              if (r16 == 0)
                atomicAdd(&rsn[(size_t)n * QP + (hh + 1) * 30 + (ww2 + 1)], rowsum);
            }
          }
        }
      }
      __syncthreads();
      // x1T writeout: 256 o x 128 q (64KB) -> 128B/thread
      {
        const int o_l = t >> 1, qseg = (t & 1) * 64;
        short* x1s = (short*)x1t;
        const size_t gbase = ((size_t)(n * CCH + o_l)) * QO + qt + h * 128 + qseg;
#pragma unroll
        for (int j = 0; j < 8; ++j)
          *(short8*)(x1s + gbase + j * 8) = *(const short8*)&tb[o_l * 136 + qseg + j * 8];
      }
      // Xp2 writeout: 128 q x 256 o -> 64B/thread
      {
        const int row = t >> 2, seg = (t & 3) * 64;
        const int q = qt + h * 128 + row;
        const int hh = q / 30, ww2 = q % 30;
        if (hh < HW && ww2 < HW) {
          int8_t* dst = xpn + ((size_t)n * QP + (hh + 1) * 30 + (ww2 + 1)) * CCH + seg;
          const int8_t* srcl = xpb + row * 256 + seg;
#pragma unroll
          for (int j = 0; j < 4; ++j)
            *(i32x4*)(dst + j * 16) = *(const i32x4*)(srcl + j * 16);
        }
      }
      __syncthreads();
    }
  } else {
    // D[o = rw*128 + m*16 + g4 + r][q = qt + cw*64 + nn*16 + r16]
    float* cst = (float*)lds;             // [5][256] f32 (A region, dead)
    if (t < 256) {
      const int o = t;
      const float inv = bng[o] / sqrtf(bnv[o] + 1e-5f);
      cst[o]        = am[o] * inv;
      cst[256 + o]  = am[CCH + o] * inv;
      cst[512 + o]  = bnb[o] - bnm[o] * inv;
      cst[768 + o]  = pos[o];
      cst[1024 + o] = neg[o];
    }
    __syncthreads();                      // cst + ldsT visible
    float tqv[4];
#pragma unroll
    for (int nn = 0; nn < 4; ++nn)
      tqv[nn] = ldsT[cw * 64 + nn * 16 + r16];
#pragma unroll
    for (int nn = 0; nn < 4; ++nn) {
      const int q = qt + cw * 64 + nn * 16 + r16;
      const int hh = q / 30, ww2 = q % 30;
      const bool valid = (hh < HW) && (ww2 < HW);
      const float tq = tqv[nn];
#pragma unroll
      for (int m = 0; m < 8; ++m) {
#pragma unroll
        for (int r = 0; r < 4; ++r) {
          const int o = rw * 128 + m * 16 + g4 + r;
          if (valid) {
            float v = cst[o] * (float)acc[m][nn][r] + cst[256 + o] * tq + cst[512 + o];
            v += __bfloat162float(x1r[((size_t)(n * CCH + o)) * QO + q]);
            v = v > 0.f ? cst[768 + o] * v : cst[1024 + o] * v;
            out[((size_t)(n * CCH + o)) * PLN + hh * HW + ww2] = v;
          }
        }
      }
    }
  }
}

extern "C" void kernel_launch(void* const* d_in, const int* in_sizes, int n_in,
                              void* d_out, int out_size, void* d_ws, size_t ws_size,
                              hipStream_t stream) {
  const float* x   = (const float*)d_in[0];
  const float* w1  = (const float*)d_in[1];
  const float* al1 = (const float*)d_in[2];
  const float* be1 = (const float*)d_in[3];
  const float* g1  = (const float*)d_in[4];
  const float* bb1 = (const float*)d_in[5];
  const float* m1  = (const float*)d_in[6];
  const float* v1  = (const float*)d_in[7];
  const float* p1  = (const float*)d_in[8];
  const float* n1  = (const float*)d_in[9];
  const float* w2  = (const float*)d_in[10];
  const float* al2 = (const float*)d_in[11];
  const float* be2 = (const float*)d_in[12];
  const float* g2  = (const float*)d_in[13];
  const float* bb2 = (const float*)d_in[14];
  const float* m2  = (const float*)d_in[15];
  const float* v2  = (const float*)d_in[16];
  const float* p2  = (const float*)d_in[17];
  const float* n2  = (const float*)d_in[18];
  float* out = (float*)d_out;

  char* ws = (char*)d_ws;
  // workspace layout:
  //   Xp1 @0          : 17,825,792  i8 [64][1088][256]
  //   Xp2 @17,825,792 : 17,825,792
  //   x1T @35,651,584 : 33,554,432  bf16 [64][256][1024]
  //   Aw1 @69,206,016 :    589,824  i8 [256][2304]
  //   Aw2 @69,795,840 :    589,824
  //   am1 @70,385,664 :      2,048
  //   am2 @70,387,712 :      2,048
  //   rs1 @70,389,760 :    278,528  f32 [64][1088]
  //   rs2 @70,668,288 :    278,528   (total 70,946,816)
  int8_t* Xp1 = (int8_t*)(ws);
  int8_t* Xp2 = (int8_t*)(ws + 17825792);
  bf16*   X1T = (bf16*)(ws + 35651584);
  int8_t* Aw1 = (int8_t*)(ws + 69206016);
  int8_t* Aw2 = (int8_t*)(ws + 69795840);
  float*  am1 = (float*)(ws + 70385664);
  float*  am2 = (float*)(ws + 70387712);
  float*  rs1 = (float*)(ws + 70389760);
  float*  rs2 = (float*)(ws + 70668288);
  float*  xT  = out;  // scratch; kconv2 overwrites with final output

  kinit<<<248, 256, 0, stream>>>(Xp1, Xp2, (i32x4*)rs1);
  kwprep<<<512, 256, 0, stream>>>(w1, w2, Aw1, Aw2, am1, am2);
  kaprep<<<NIMG * HW, 256, 0, stream>>>(x, al1, be1, Xp1, rs1, xT);
  kconv<1><<<256, 512, 0, stream>>>(Xp1, Aw1, am1, rs1, g1, bb1, m1, v1, p1, n1,
                                    xT, nullptr, al2, be2, Xp2, X1T, rs2, nullptr);
  kconv<2><<<256, 512, 0, stream>>>(Xp2, Aw2, am2, rs2, g2, bb2, m2, v2, p2, n2,
                                    nullptr, X1T, nullptr, nullptr, nullptr, nullptr,
                                    nullptr, out);
}

// Round 18
// 149.434 us; speedup vs baseline: 1.2899x; 1.2899x over previous
//
#include <hip/hip_runtime.h>
#include <hip/hip_bf16.h>

using bf16 = __hip_bfloat16;
typedef __attribute__((ext_vector_type(8))) short short8;
typedef __attribute__((ext_vector_type(4))) float f32x4;
typedef __attribute__((ext_vector_type(4))) int i32x4;

#define QP   960
#define QO   896
#define KTOT 2304
#define NIMG 64
#define CCH  256
#define HW   28
#define PLN  784

__device__ __forceinline__ void gload_lds16(const void* g, void* l) {
  __builtin_amdgcn_global_load_lds((const __attribute__((address_space(1))) void*)g,
                                   (__attribute__((address_space(3))) void*)l, 16, 0, 0);
}

// ------- init: zero Xp borders/tails (i8) + zero rs1/rs2 --------------------
__global__ __launch_bounds__(256) void kinit(int8_t* __restrict__ xp1,
                                             int8_t* __restrict__ xp2,
                                             i32x4* __restrict__ rsz) {
  const int b = blockIdx.x;
  const int t = threadIdx.x;
  const i32x4 z = {0, 0, 0, 0};
  if (b < 128) {
    const int n = b >> 1;
    int8_t* xp = (b & 1) ? xp2 : xp1;
#pragma unroll
    for (int p = 0; p < 11; ++p) {
      const int task = p * 256 + t;
      const int r = task >> 4, l16 = task & 15;
      int q;
      if (r < 30) q = r;
      else if (r < 60) q = 870 + (r - 30);
      else if (r < 120) q = 900 + (r - 60);
      else { const int k = r - 120; q = (1 + (k >> 1)) * 30 + ((k & 1) ? 29 : 0); }
      ((i32x4*)(xp + ((size_t)n * QP + q) * CCH))[l16] = z;
    }
  } else {
    rsz[(b - 128) * 256 + t] = z;
  }
}

// ---------------- weight prep ------------------------------------------------
__global__ __launch_bounds__(256) void kwprep(const float* __restrict__ w1,
                                              const float* __restrict__ w2,
                                              int8_t* __restrict__ aw1,
                                              int8_t* __restrict__ aw2,
                                              float* __restrict__ am1,
                                              float* __restrict__ am2) {
  const int o = blockIdx.x & 255;
  const float* w = (blockIdx.x >> 8) ? w2 : w1;
  int8_t* aw = (blockIdx.x >> 8) ? aw2 : aw1;
  float* am = (blockIdx.x >> 8) ? am2 : am1;
  const int t = threadIdx.x;
  const int lane = t & 63, wid = t >> 6;
  const float* wo = w + (size_t)o * KTOT;
  float v[9];
  double s = 0.0;
#pragma unroll
  for (int j = 0; j < 9; ++j) { v[j] = wo[t * 9 + j]; s += (double)v[j]; }
  __shared__ double red[4];
#pragma unroll
  for (int m = 32; m >= 1; m >>= 1) s += __shfl_xor(s, m);
  if (lane == 0) red[wid] = s;
  __syncthreads();
  const double mean = (red[0] + red[1] + red[2] + red[3]) * (1.0 / 2304.0);
  __syncthreads();
  double sq = 0.0;
#pragma unroll
  for (int j = 0; j < 9; ++j) { const double d = (double)v[j] - mean; sq += d * d; }
#pragma unroll
  for (int m = 32; m >= 1; m >>= 1) sq += __shfl_xor(sq, m);
  if (lane == 0) red[wid] = sq;
  __syncthreads();
  const double alpha = sqrt((red[0] + red[1] + red[2] + red[3]) * (1.0 / 2304.0));
#pragma unroll
  for (int j = 0; j < 9; ++j) {
    const double d = (double)v[j] - mean;
    const int sg = d > 0.0 ? 1 : (d < 0.0 ? -1 : 0);
    aw[(size_t)o * KTOT + j * CCH + t] = (int8_t)sg;
  }
  if (t == 0) { am[o] = (float)alpha; am[CCH + o] = (float)mean; }
}

// -------- activation signs + row sums + transposed residual -----------------
__global__ __launch_bounds__(256) void kaprep(const float* __restrict__ x,
                                              const float* __restrict__ alpha,
                                              const float* __restrict__ beta,
                                              int8_t* __restrict__ xp,
                                              float* __restrict__ rs,
                                              float* __restrict__ xT) {
  const int n = blockIdx.x / HW;
  const int h = blockIdx.x % HW;
  const int c = threadIdx.x;
  const float a = alpha[c], bt = beta[c];
  const float* src = x + ((size_t)(n * CCH + c)) * PLN + h * HW;
  __shared__ int8_t tile[CCH][HW];
#pragma unroll
  for (int j = 0; j < 7; ++j) {
    float4 f = ((const float4*)src)[j];
    float vv[4] = {f.x, f.y, f.z, f.w};
#pragma unroll
    for (int e = 0; e < 4; ++e) {
      const float xa = (vv[e] - bt) / a;
      const float sg = xa > 0.f ? 1.f : (xa < 0.f ? -1.f : 0.f);
      tile[c][j * 4 + e] = (int8_t)__float2int_rn(sg * a + bt);
      xT[((size_t)n * PLN + h * HW + j * 4 + e) * CCH + c] = vv[e];
    }
  }
  __syncthreads();
  int8_t* dst = xp + ((size_t)n * QP + (h + 1) * 30 + 1) * CCH;
#pragma unroll
  for (int ww = 0; ww < HW; ++ww) dst[ww * CCH + c] = tile[c][ww];
  const int ww = c >> 3, sub = c & 7;
  if (ww < HW) {
    int s = 0;
#pragma unroll
    for (int cc = 0; cc < 32; ++cc) s += (int)tile[sub * 32 + cc][ww];
    s += __shfl_xor(s, 4); s += __shfl_xor(s, 2); s += __shfl_xor(s, 1);
    if (sub == 0) rs[(size_t)n * QP + (h + 1) * 30 + 1 + ww] = (float)s;
  }
}

// ---------------- implicit-GEMM conv: 8-wave (512-thread) blocks ------------
// Same 128x128 tile, persistent A (48KB) + B 3-ring, counted vmcnt(1).
// Per-wave tile 64x32: rw = wid>>2 (2 row blocks), cw = wid&3 (4 col blocks).
// acc[4][2]; 8 MFMA/iter/wave. 2 blocks/CU -> 16 waves/CU (4/SIMD).
// EPI1 (D[q][o]): rows=pixels(A-LDS), cols=weights(B). EPI2 (D[o][q]):
// rows=weights(B), cols=pixels(A-LDS) — w-contiguous out writes preserved.
template <int EPI>
__global__ __launch_bounds__(512, 4) void kconv(
    const int8_t* __restrict__ xp, const int8_t* __restrict__ aw,
    const float* __restrict__ am, const float* __restrict__ rs,
    const float* __restrict__ bng, const float* __restrict__ bnb,
    const float* __restrict__ bnm, const float* __restrict__ bnv,
    const float* __restrict__ pos, const float* __restrict__ neg,
    const float* __restrict__ xT, const bf16* __restrict__ x1r,
    const float* __restrict__ a2, const float* __restrict__ b2,
    int8_t* __restrict__ xpn, bf16* __restrict__ x1t,
    float* __restrict__ rsn, float* __restrict__ out)
{
  __shared__ char lds[73728];           // A 48K @0 + B ring 3*8K @49152
  char* ldsB = lds + 49152;
  float* ldsT = (float*)(lds + 73216);  // tail of B-buf2 (dead post-loop)
  const int bid0 = blockIdx.x;
  const int bid = (bid0 & 7) * 112 + (bid0 >> 3);
  const int nt = bid & 1;
  const int mt = bid >> 1;
  const int n = mt / 7;
  const int qt = (mt % 7) * 128;
  const int o0 = nt * 128;
  const int t = threadIdx.x;
  const int lane = t & 63, wid = t >> 6;
  const int rw = wid >> 2, cw = wid & 3;

  // B staging: one 16B chunk per thread (byte-identical layout to r9)
  const int rowp = t >> 3;              // lds-row 0..63
  const int pcS = t & 7;
  const int cS = pcS ^ (rowp & 7);
  const int pS = cS >> 2;
  const int k16S = cS & 3;

  i32x4 acc[4][2];
#pragma unroll
  for (int i = 0; i < 4; ++i)
#pragma unroll
    for (int j = 0; j < 2; ++j) acc[i][j] = (i32x4){0, 0, 0, 0};

  const int r16 = lane & 15;
  const int g = lane >> 4;
  const int g4 = g * 4;
  const int rsh = r16 >> 1;
  const int pc0 = ((r16 & 1) * 4 + g) ^ rsh;
  // operand-block bases:
  const int aoff = (EPI == 1) ? rw * 64 : cw * 32;   // pixel-row base (A region)
  const int bbase = (EPI == 1) ? cw * 16 : rw * 32;  // weight lds-row base (B)

  const int8_t* baseB = aw + ((size_t)(o0 + 2 * rowp + pS)) * KTOT + k16S * 16;

  auto STAGE_B = [&](int buf, int ks) {
    gload_lds16(baseB + (size_t)ks * 64, ldsB + buf * 8192 + rowp * 128 + pcS * 16);
  };

  {  // persistent-A prologue: 3040 tasks over 512 threads
    const int8_t* imgA = xp + ((size_t)(n * QP + qt)) * CCH;
#pragma unroll
    for (int i = 0; i < 6; ++i) {
      const int task = t + i * 512;
      if (task < 3040) {
        const int rr = task >> 4, pc = task & 15;
        gload_lds16(imgA + (size_t)rr * CCH + ((pc ^ (rr & 15)) * 16),
                    lds + rr * 256 + pc * 16);
      }
    }
  }
  STAGE_B(0, 0);
  STAGE_B(1, 1);
  asm volatile("s_waitcnt vmcnt(1)" ::: "memory");   // A + B0 complete
  __builtin_amdgcn_s_barrier();

#pragma unroll
  for (int ks = 0; ks < 36; ++ks) {
    const int tap = ks >> 2, ksl = ks & 3;
    const int shc = (tap / 3) * 30 + (tap % 3);
    const int cur = ks % 3;
    const int achunk = ((ksl * 4 + g) ^ ((r16 + shc) & 15)) * 16;
    const char* pA = lds + (shc + aoff + r16) * 256 + achunk;
    const char* pB = ldsB + cur * 8192;
    i32x4 fR[4], fC[2];
    if constexpr (EPI == 1) {
#pragma unroll
      for (int m = 0; m < 4; ++m) fR[m] = *(const i32x4*)&pA[m * 4096];
#pragma unroll
      for (int nn = 0; nn < 2; ++nn)
        fC[nn] = *(const i32x4*)&pB[(bbase + nn * 8 + rsh) * 128 + pc0 * 16];
    } else {
#pragma unroll
      for (int m = 0; m < 4; ++m)
        fR[m] = *(const i32x4*)&pB[(bbase + m * 8 + rsh) * 128 + pc0 * 16];
#pragma unroll
      for (int nn = 0; nn < 2; ++nn) fC[nn] = *(const i32x4*)&pA[nn * 4096];
    }
    if (ks < 34) STAGE_B((ks + 2) % 3, ks + 2);
    __builtin_amdgcn_s_setprio(1);
#pragma unroll
    for (int m = 0; m < 4; ++m)
#pragma unroll
      for (int nn = 0; nn < 2; ++nn)
        acc[m][nn] = __builtin_amdgcn_mfma_i32_16x16x64_i8(
            fR[m], fC[nn], acc[m][nn], 0, 0, 0);
    __builtin_amdgcn_s_setprio(0);
    if (ks < 34) {
      asm volatile("s_waitcnt vmcnt(1)" ::: "memory");
    } else {
      asm volatile("s_waitcnt vmcnt(0)" ::: "memory");
    }
    __builtin_amdgcn_s_barrier();
  }

  // ---- per-block T into dead LDS --------------------------------------------
  if (t < 128) {
    const float* rrow = rs + (size_t)n * QP + qt + t;
    float s = 0.f;
#pragma unroll
    for (int kh = 0; kh < 3; ++kh)
#pragma unroll
      for (int kw = 0; kw < 3; ++kw) s += rrow[kh * 30 + kw];
    ldsT[t] = s;
  }

  if constexpr (EPI == 1) {
    // D[q = qt + rw*64 + m*16 + g4 + r][o = o0 + cw*32 + nn*16 + r16]
    int oc[2];
    float invc[2], addc[2], ppc[2], ngc[2], awc[2], mwc[2], aac[2], bbc[2];
#pragma unroll
    for (int nn = 0; nn < 2; ++nn) {
      const int o = o0 + cw * 32 + nn * 16 + r16;
      oc[nn] = o;
      const float inv = bng[o] / sqrtf(bnv[o] + 1e-5f);
      invc[nn] = inv;
      addc[nn] = bnb[o] - bnm[o] * inv;
      ppc[nn] = pos[o]; ngc[nn] = neg[o];
      awc[nn] = am[o];  mwc[nn] = am[CCH + o];
      aac[nn] = a2[o];  bbc[nn] = b2[o];
    }
    __syncthreads();                    // ldsT visible; loop LDS reusable
    float tqv[4][4];
#pragma unroll
    for (int m = 0; m < 4; ++m)
#pragma unroll
      for (int r = 0; r < 4; ++r)
        tqv[m][r] = ldsT[rw * 64 + m * 16 + g4 + r];
    short* tb = (short*)lds;               // x1 [128 o][136 q] @0 (34.8KB)
    int8_t* xpb = (int8_t*)(lds + 36864);  // Xp2 [128 q][128 o] (16KB)
#pragma unroll
    for (int m = 0; m < 4; ++m) {
#pragma unroll
      for (int r = 0; r < 4; ++r) {
        const int ql = rw * 64 + m * 16 + g4 + r;
        const int q = qt + ql;
        const int hh = q / 30, ww2 = q % 30;
        if (hh < HW && ww2 < HW) {
          const float tq = tqv[m][r];
          const float* xrow = xT + ((size_t)n * PLN + hh * HW + ww2) * CCH;
          float rowsum = 0.f;
#pragma unroll
          for (int nn = 0; nn < 2; ++nn) {
            const int ol = cw * 32 + nn * 16 + r16;
            float v = awc[nn] * (float)acc[m][nn][r] + mwc[nn] * tq;
            v = v * invc[nn] + addc[nn];
            v += xrow[oc[nn]];
            v = v > 0.f ? ppc[nn] * v : ngc[nn] * v;
            const float d = v - bbc[nn];
            const float sg = d > 0.f ? 1.f : (d < 0.f ? -1.f : 0.f);
            const float bv = sg * aac[nn] + bbc[nn];
            rowsum += bv;
            xpb[ql * 128 + ol] = (int8_t)__float2int_rn(bv);
            bf16 hb = __float2bfloat16(v);
            tb[ol * 136 + ql] = *reinterpret_cast<short*>(&hb);
          }
          rowsum += __shfl_xor(rowsum, 8); rowsum += __shfl_xor(rowsum, 4);
          rowsum += __shfl_xor(rowsum, 2); rowsum += __shfl_xor(rowsum, 1);
          if (r16 == 0)
            atomicAdd(&rsn[(size_t)n * QP + (hh + 1) * 30 + (ww2 + 1)], rowsum);
        }
      }
    }
    __syncthreads();
    // x1T transpose readout: 512 threads, 64B each
    {
      const int o_l = t >> 2, qq = (t & 3) * 32;
      short* x1s = (short*)x1t;
      const size_t gbase = ((size_t)(n * CCH + o0 + o_l)) * QO + qt + qq;
#pragma unroll
      for (int j = 0; j < 4; ++j)
        *(short8*)(x1s + gbase + j * 8) = *(const short8*)&tb[o_l * 136 + qq + j * 8];
    }
    // Xp2 writeout: 512 threads, 32B each
    {
      const int row = t >> 2, qtr = t & 3;
      const int q = qt + row;
      const int hh = q / 30, ww2 = q % 30;
      if (hh < HW && ww2 < HW) {
        int8_t* dst = xpn + ((size_t)n * QP + (hh + 1) * 30 + (ww2 + 1)) * CCH
                      + o0 + qtr * 32;
        const int8_t* srcl = xpb + row * 128 + qtr * 32;
        *(i32x4*)dst = *(const i32x4*)srcl;
        *(i32x4*)(dst + 16) = *(const i32x4*)(srcl + 16);
      }
    }
  } else {
    // D[o = o0 + rw*64 + m*16 + g4 + r][q = qt + cw*32 + nn*16 + r16]
    float* cst = (float*)lds;
    if (t < 128) {
      const int o = o0 + t;
      const float inv = bng[o] / sqrtf(bnv[o] + 1e-5f);
      cst[t]       = am[o] * inv;
      cst[128 + t] = am[CCH + o] * inv;
      cst[256 + t] = bnb[o] - bnm[o] * inv;
      cst[384 + t] = pos[o];
      cst[512 + t] = neg[o];
    }
    __syncthreads();                    // cst + ldsT visible
    float tqv[2];
#pragma unroll
    for (int nn = 0; nn < 2; ++nn)
      tqv[nn] = ldsT[cw * 32 + nn * 16 + r16];
#pragma unroll
    for (int nn = 0; nn < 2; ++nn) {
      const int q = qt + cw * 32 + nn * 16 + r16;
      const int hh = q / 30, ww2 = q % 30;
      const bool valid = (hh < HW) && (ww2 < HW);
      const float tq = tqv[nn];
#pragma unroll
      for (int m = 0; m < 4; ++m) {
#pragma unroll
        for (int r = 0; r < 4; ++r) {
          const int ol = rw * 64 + m * 16 + g4 + r;
          const int o = o0 + ol;
          if (valid) {
            float v = cst[ol] * (float)acc[m][nn][r] + cst[128 + ol] * tq + cst[256 + ol];
            v += __bfloat162float(x1r[((size_t)(n * CCH + o)) * QO + q]);
            v = v > 0.f ? cst[384 + ol] * v : cst[512 + ol] * v;
            out[((size_t)(n * CCH + o)) * PLN + hh * HW + ww2] = v;
          }
        }
      }
    }
  }
}

extern "C" void kernel_launch(void* const* d_in, const int* in_sizes, int n_in,
                              void* d_out, int out_size, void* d_ws, size_t ws_size,
                              hipStream_t stream) {
  const float* x   = (const float*)d_in[0];
  const float* w1  = (const float*)d_in[1];
  const float* al1 = (const float*)d_in[2];
  const float* be1 = (const float*)d_in[3];
  const float* g1  = (const float*)d_in[4];
  const float* bb1 = (const float*)d_in[5];
  const float* m1  = (const float*)d_in[6];
  const float* v1  = (const float*)d_in[7];
  const float* p1  = (const float*)d_in[8];
  const float* n1  = (const float*)d_in[9];
  const float* w2  = (const float*)d_in[10];
  const float* al2 = (const float*)d_in[11];
  const float* be2 = (const float*)d_in[12];
  const float* g2  = (const float*)d_in[13];
  const float* bb2 = (const float*)d_in[14];
  const float* m2  = (const float*)d_in[15];
  const float* v2  = (const float*)d_in[16];
  const float* p2  = (const float*)d_in[17];
  const float* n2  = (const float*)d_in[18];
  float* out = (float*)d_out;

  char* ws = (char*)d_ws;
  int8_t* Xp1 = (int8_t*)(ws);
  int8_t* Xp2 = (int8_t*)(ws + 15728640);
  bf16*   X1T = (bf16*)(ws + 31457280);
  int8_t* Aw1 = (int8_t*)(ws + 60817408);
  int8_t* Aw2 = (int8_t*)(ws + 61407232);
  float*  am1 = (float*)(ws + 61997056);
  float*  am2 = (float*)(ws + 61999104);
  float*  rs1 = (float*)(ws + 62001152);
  float*  rs2 = (float*)(ws + 62246912);
  float*  xT  = out;  // scratch; kconv2 overwrites with final output

  kinit<<<248, 256, 0, stream>>>(Xp1, Xp2, (i32x4*)rs1);
  kwprep<<<512, 256, 0, stream>>>(w1, w2, Aw1, Aw2, am1, am2);
  kaprep<<<NIMG * HW, 256, 0, stream>>>(x, al1, be1, Xp1, rs1, xT);
  kconv<1><<<896, 512, 0, stream>>>(Xp1, Aw1, am1, rs1, g1, bb1, m1, v1, p1, n1,
                                    xT, nullptr, al2, be2, Xp2, X1T, rs2, nullptr);
  kconv<2><<<896, 512, 0, stream>>>(Xp2, Aw2, am2, rs2, g2, bb2, m2, v2, p2, n2,
                                    nullptr, X1T, nullptr, nullptr, nullptr, nullptr,
                                    nullptr, out);
}